// Round 1
// baseline (3650.108 us; speedup 1.0000x reference)
//
#include <hip/hip_runtime.h>
#include <cstddef>

// Problem constants (from reference)
#define N0 200000
#define N1 50000
#define N2 10000
#define E0 800000
#define E1 160000
// feature dims: IN=H1=H2=256, EMB=128. K is always 256.

// ---------------- degree count: scattered atomics ----------------
__global__ void deg_kernel(const int* __restrict__ src, const int* __restrict__ dst,
                           float* __restrict__ outdeg, float* __restrict__ indeg, int E) {
    int i = blockIdx.x * 256 + threadIdx.x;
    if (i < E) {
        atomicAdd(&outdeg[src[i]], 1.0f);
        atomicAdd(&indeg[dst[i]], 1.0f);
    }
}

// ---------------- in-place rsqrt(max(x,1)) ----------------
__global__ void rsqrt_kernel(float* __restrict__ x, int n) {
    int i = blockIdx.x * 256 + threadIdx.x;
    if (i < n) x[i] = rsqrtf(fmaxf(x[i], 1.0f));
}

// ---------------- edge scatter: one wave per edge, 64 lanes x float4 = 256 floats ----------------
__global__ void scatter_kernel(const float* __restrict__ hsrc, const float* __restrict__ rs_src,
                               const int* __restrict__ src, const int* __restrict__ dst,
                               float* __restrict__ agg, int E) {
    int w    = (blockIdx.x * 256 + threadIdx.x) >> 6;   // wave id = edge id
    int lane = threadIdx.x & 63;
    if (w >= E) return;
    int s = src[w];
    int d = dst[w];
    float sc = rs_src[s];
    const float4* row = (const float4*)(hsrc + (size_t)s * 256);
    float4 v = row[lane];
    float* out = agg + (size_t)d * 256 + lane * 4;
    atomicAdd(out + 0, v.x * sc);
    atomicAdd(out + 1, v.y * sc);
    atomicAdd(out + 2, v.z * sc);
    atomicAdd(out + 3, v.w * sc);
}

// ---------------- fp32 GEMM, K=256 fixed: C[M,N] = (diag(rs)*A) @ B + bias ----------------
// BM=BN=64, BK=16, 256 threads, 4x4 per thread. rs may be nullptr (no row scale).
__global__ __launch_bounds__(256) void gemm_k256(const float* __restrict__ A,
                                                 const float* __restrict__ rs,
                                                 const float* __restrict__ B,
                                                 const float* __restrict__ bias,
                                                 float* __restrict__ C, int M, int N) {
    __shared__ float As[16][64];  // A^T tile: As[k][row]
    __shared__ float Bs[16][64];  // Bs[k][col]

    const int tidx = threadIdx.x;
    const int tx = tidx & 15;   // col group
    const int ty = tidx >> 4;   // row group
    const int rowBase = blockIdx.x * 64;
    const int colBase = blockIdx.y * 64;

    // A staging mapping: each thread loads one float4 along K
    const int arow = tidx >> 2;      // 0..63
    const int kch  = tidx & 3;       // 0..3 (float4 chunk within BK=16)
    const int grow = min(rowBase + arow, M - 1);   // clamp for OOB rows (not stored)
    const float scale = rs ? rs[grow] : 1.0f;
    const float* Arow = A + (size_t)grow * 256;

    // B staging mapping
    const int bk = tidx >> 4;        // 0..15
    const int bc = tidx & 15;        // 0..15 (float4 chunk within 64 cols)

    float acc[4][4];
#pragma unroll
    for (int i = 0; i < 4; i++)
#pragma unroll
        for (int j = 0; j < 4; j++) acc[i][j] = 0.0f;

    for (int kb = 0; kb < 256; kb += 16) {
        // stage A (transposed, scaled)
        float4 a = *(const float4*)(Arow + kb + kch * 4);
        a.x *= scale; a.y *= scale; a.z *= scale; a.w *= scale;
        As[kch * 4 + 0][arow] = a.x;
        As[kch * 4 + 1][arow] = a.y;
        As[kch * 4 + 2][arow] = a.z;
        As[kch * 4 + 3][arow] = a.w;
        // stage B
        float4 b = *(const float4*)(B + (size_t)(kb + bk) * N + colBase + bc * 4);
        *(float4*)&Bs[bk][bc * 4] = b;
        __syncthreads();

#pragma unroll
        for (int kk = 0; kk < 16; kk++) {
            float4 af = ((const float4*)As[kk])[ty];
            float4 bf = ((const float4*)Bs[kk])[tx];
            acc[0][0] += af.x * bf.x; acc[0][1] += af.x * bf.y; acc[0][2] += af.x * bf.z; acc[0][3] += af.x * bf.w;
            acc[1][0] += af.y * bf.x; acc[1][1] += af.y * bf.y; acc[1][2] += af.y * bf.z; acc[1][3] += af.y * bf.w;
            acc[2][0] += af.z * bf.x; acc[2][1] += af.z * bf.y; acc[2][2] += af.z * bf.z; acc[2][3] += af.z * bf.w;
            acc[3][0] += af.w * bf.x; acc[3][1] += af.w * bf.y; acc[3][2] += af.w * bf.z; acc[3][3] += af.w * bf.w;
        }
        __syncthreads();
    }

    float4 bias4 = ((const float4*)(bias + colBase))[tx];
#pragma unroll
    for (int i = 0; i < 4; i++) {
        int row = rowBase + ty * 4 + i;
        if (row < M) {
            float4 o;
            o.x = acc[i][0] + bias4.x;
            o.y = acc[i][1] + bias4.y;
            o.z = acc[i][2] + bias4.z;
            o.w = acc[i][3] + bias4.w;
            *(float4*)(C + (size_t)row * N + colBase + tx * 4) = o;
        }
    }
}

extern "C" void kernel_launch(void* const* d_in, const int* in_sizes, int n_in,
                              void* d_out, int out_size, void* d_ws, size_t ws_size,
                              hipStream_t stream) {
    const float* h    = (const float*)d_in[0];
    const int*   src0 = (const int*)d_in[1];
    const int*   dst0 = (const int*)d_in[2];
    const int*   src1 = (const int*)d_in[3];
    const int*   dst1 = (const int*)d_in[4];
    const float* W1   = (const float*)d_in[5];
    const float* b1   = (const float*)d_in[6];
    const float* W2   = (const float*)d_in[7];
    const float* b2   = (const float*)d_in[8];
    const float* Wp   = (const float*)d_in[9];
    const float* bp   = (const float*)d_in[10];
    float* out = (float*)d_out;

    // workspace layout (floats)
    float* ws = (float*)d_ws;
    float* deg_out0 = ws;                               // N0
    float* deg_in0  = deg_out0 + N0;                    // N1
    float* deg_out1 = deg_in0 + N1;                     // N1
    float* deg_in1  = deg_out1 + N1;                    // N2
    float* agg0     = deg_in1 + N2;                     // N1*256
    float* agg1     = agg0 + (size_t)N1 * 256;          // N2*256
    float* h1       = agg1 + (size_t)N2 * 256;          // N1*256
    float* h2       = h1 + (size_t)N1 * 256;            // N2*256
    const size_t n_degs = (size_t)N0 + 2 * N1 + N2;     // 310000
    const size_t zero_bytes = (n_degs + (size_t)N1 * 256 + (size_t)N2 * 256) * sizeof(float);

    // 1. zero degrees + agg buffers
    hipMemsetAsync(d_ws, 0, zero_bytes, stream);

    // 2. degree counts
    deg_kernel<<<(E0 + 255) / 256, 256, 0, stream>>>(src0, dst0, deg_out0, deg_in0, E0);
    deg_kernel<<<(E1 + 255) / 256, 256, 0, stream>>>(src1, dst1, deg_out1, deg_in1, E1);

    // 3. rsqrt(max(deg,1)) in place across all 4 degree arrays (contiguous)
    rsqrt_kernel<<<((int)n_degs + 255) / 256, 256, 0, stream>>>(ws, (int)n_degs);

    // 4. layer-1 scatter: agg0[dst] += rs_out0[src] * h[src]
    scatter_kernel<<<E0 / 4, 256, 0, stream>>>(h, deg_out0, src0, dst0, agg0, E0);

    // 5. h1 = (diag(rs_in0) agg0) @ W1 + b1    [50000 x 256]
    gemm_k256<<<dim3((N1 + 63) / 64, 4), 256, 0, stream>>>(agg0, deg_in0, W1, b1, h1, N1, 256);

    // 6. layer-2 scatter: agg1[dst] += rs_out1[src] * h1[src]
    scatter_kernel<<<E1 / 4, 256, 0, stream>>>(h1, deg_out1, src1, dst1, agg1, E1);

    // 7. h2 = (diag(rs_in1) agg1) @ W2 + b2    [10000 x 256]
    gemm_k256<<<dim3((N2 + 63) / 64, 4), 256, 0, stream>>>(agg1, deg_in1, W2, b2, h2, N2, 256);

    // 8. out = h2 @ Wp + bp                    [10000 x 128]
    gemm_k256<<<dim3((N2 + 63) / 64, 2), 256, 0, stream>>>(h2, nullptr, Wp, bp, out, N2, 128);
}

// Round 2
// 748.980 us; speedup vs baseline: 4.8734x; 4.8734x over previous
//
#include <hip/hip_runtime.h>
#include <cstddef>

// Problem constants (from reference)
#define N0 200000
#define N1 50000
#define N2 10000
#define E0 800000
#define E1 160000
// feature dims: IN=H1=H2=256, EMB=128. K is always 256.

// ---------------- pass A: out-degree count + in-degree count with per-edge rank ----------------
__global__ void count_kernel(const int* __restrict__ src, const int* __restrict__ dst,
                             int* __restrict__ out_cnt, int* __restrict__ in_cnt,
                             int* __restrict__ rank, int E) {
    int e = blockIdx.x * 256 + threadIdx.x;
    if (e < E) {
        atomicAdd(&out_cnt[src[e]], 1);
        rank[e] = atomicAdd(&in_cnt[dst[e]], 1);
    }
}

// ---------------- counts -> rsqrt(max(cnt,1)) scales ----------------
__global__ void scales_kernel(const int* __restrict__ cnt, float* __restrict__ rs, int n) {
    int i = blockIdx.x * 256 + threadIdx.x;
    if (i < n) rs[i] = rsqrtf((float)max(cnt[i], 1));
}

// ---------------- single-workgroup 3-phase exclusive scan: rowptr[0..n] ----------------
__global__ __launch_bounds__(1024) void scan_kernel(const int* __restrict__ cnt,
                                                    int* __restrict__ rowptr, int n) {
    __shared__ int partial[1024];
    const int t = threadIdx.x;
    const int chunk = (n + 1023) / 1024;
    const int begin = t * chunk;
    const int end = min(begin + chunk, n);
    int sum = 0;
    for (int i = begin; i < end; i++) sum += cnt[i];
    partial[t] = sum;
    __syncthreads();
    // Hillis-Steele inclusive scan over the 1024 partials
    for (int off = 1; off < 1024; off <<= 1) {
        int v = (t >= off) ? partial[t - off] : 0;
        __syncthreads();
        partial[t] += v;
        __syncthreads();
    }
    int run = partial[t] - sum;   // exclusive prefix of this thread's chunk
    for (int i = begin; i < end; i++) {
        rowptr[i] = run;
        run += cnt[i];
    }
    if (t == 1023) rowptr[n] = partial[1023];
}

// ---------------- pass C: drop src indices into CSR slots ----------------
__global__ void fill_kernel(const int* __restrict__ src, const int* __restrict__ dst,
                            const int* __restrict__ rank, const int* __restrict__ rowptr,
                            int* __restrict__ csr, int E) {
    int e = blockIdx.x * 256 + threadIdx.x;
    if (e < E) csr[rowptr[dst[e]] + rank[e]] = src[e];
}

// ---------------- gather: one wave per dst row, 64 lanes x float4 = 256 floats ----------------
__global__ __launch_bounds__(256) void gather_kernel(const float* __restrict__ hsrc,
                                                     const float* __restrict__ rs_src,
                                                     const int* __restrict__ rowptr,
                                                     const int* __restrict__ csr,
                                                     float* __restrict__ agg, int n_dst) {
    int w    = (blockIdx.x * 256 + threadIdx.x) >> 6;   // wave id = dst row
    int lane = threadIdx.x & 63;
    if (w >= n_dst) return;
    int e   = rowptr[w];
    int end = rowptr[w + 1];
    float4 acc = make_float4(0.f, 0.f, 0.f, 0.f);
    // unroll-2: two independent load chains in flight
    for (; e + 1 < end; e += 2) {
        int s0 = csr[e];
        int s1 = csr[e + 1];
        float sc0 = rs_src[s0];
        float sc1 = rs_src[s1];
        float4 v0 = ((const float4*)(hsrc + (size_t)s0 * 256))[lane];
        float4 v1 = ((const float4*)(hsrc + (size_t)s1 * 256))[lane];
        acc.x += v0.x * sc0; acc.y += v0.y * sc0; acc.z += v0.z * sc0; acc.w += v0.w * sc0;
        acc.x += v1.x * sc1; acc.y += v1.y * sc1; acc.z += v1.z * sc1; acc.w += v1.w * sc1;
    }
    if (e < end) {
        int s0 = csr[e];
        float sc0 = rs_src[s0];
        float4 v0 = ((const float4*)(hsrc + (size_t)s0 * 256))[lane];
        acc.x += v0.x * sc0; acc.y += v0.y * sc0; acc.z += v0.z * sc0; acc.w += v0.w * sc0;
    }
    ((float4*)(agg + (size_t)w * 256))[lane] = acc;
}

// ---------------- fp32 GEMM, K=256 fixed: C[M,N] = (diag(rs)*A) @ B + bias ----------------
// BM=BN=64, BK=16, 256 threads, 4x4 per thread. rs may be nullptr (no row scale).
__global__ __launch_bounds__(256) void gemm_k256(const float* __restrict__ A,
                                                 const float* __restrict__ rs,
                                                 const float* __restrict__ B,
                                                 const float* __restrict__ bias,
                                                 float* __restrict__ C, int M, int N) {
    __shared__ float As[16][64];  // A^T tile: As[k][row]
    __shared__ float Bs[16][64];  // Bs[k][col]

    const int tidx = threadIdx.x;
    const int tx = tidx & 15;   // col group
    const int ty = tidx >> 4;   // row group
    const int rowBase = blockIdx.x * 64;
    const int colBase = blockIdx.y * 64;

    const int arow = tidx >> 2;      // 0..63
    const int kch  = tidx & 3;       // 0..3 (float4 chunk within BK=16)
    const int grow = min(rowBase + arow, M - 1);
    const float scale = rs ? rs[grow] : 1.0f;
    const float* Arow = A + (size_t)grow * 256;

    const int bk = tidx >> 4;        // 0..15
    const int bc = tidx & 15;        // 0..15

    float acc[4][4];
#pragma unroll
    for (int i = 0; i < 4; i++)
#pragma unroll
        for (int j = 0; j < 4; j++) acc[i][j] = 0.0f;

    for (int kb = 0; kb < 256; kb += 16) {
        float4 a = *(const float4*)(Arow + kb + kch * 4);
        a.x *= scale; a.y *= scale; a.z *= scale; a.w *= scale;
        As[kch * 4 + 0][arow] = a.x;
        As[kch * 4 + 1][arow] = a.y;
        As[kch * 4 + 2][arow] = a.z;
        As[kch * 4 + 3][arow] = a.w;
        float4 b = *(const float4*)(B + (size_t)(kb + bk) * N + colBase + bc * 4);
        *(float4*)&Bs[bk][bc * 4] = b;
        __syncthreads();

#pragma unroll
        for (int kk = 0; kk < 16; kk++) {
            float4 af = ((const float4*)As[kk])[ty];
            float4 bf = ((const float4*)Bs[kk])[tx];
            acc[0][0] += af.x * bf.x; acc[0][1] += af.x * bf.y; acc[0][2] += af.x * bf.z; acc[0][3] += af.x * bf.w;
            acc[1][0] += af.y * bf.x; acc[1][1] += af.y * bf.y; acc[1][2] += af.y * bf.z; acc[1][3] += af.y * bf.w;
            acc[2][0] += af.z * bf.x; acc[2][1] += af.z * bf.y; acc[2][2] += af.z * bf.z; acc[2][3] += af.z * bf.w;
            acc[3][0] += af.w * bf.x; acc[3][1] += af.w * bf.y; acc[3][2] += af.w * bf.z; acc[3][3] += af.w * bf.w;
        }
        __syncthreads();
    }

    float4 bias4 = ((const float4*)(bias + colBase))[tx];
#pragma unroll
    for (int i = 0; i < 4; i++) {
        int row = rowBase + ty * 4 + i;
        if (row < M) {
            float4 o;
            o.x = acc[i][0] + bias4.x;
            o.y = acc[i][1] + bias4.y;
            o.z = acc[i][2] + bias4.z;
            o.w = acc[i][3] + bias4.w;
            *(float4*)(C + (size_t)row * N + colBase + tx * 4) = o;
        }
    }
}

extern "C" void kernel_launch(void* const* d_in, const int* in_sizes, int n_in,
                              void* d_out, int out_size, void* d_ws, size_t ws_size,
                              hipStream_t stream) {
    const float* h    = (const float*)d_in[0];
    const int*   src0 = (const int*)d_in[1];
    const int*   dst0 = (const int*)d_in[2];
    const int*   src1 = (const int*)d_in[3];
    const int*   dst1 = (const int*)d_in[4];
    const float* W1   = (const float*)d_in[5];
    const float* b1   = (const float*)d_in[6];
    const float* W2   = (const float*)d_in[7];
    const float* b2   = (const float*)d_in[8];
    const float* Wp   = (const float*)d_in[9];
    const float* bp   = (const float*)d_in[10];
    float* out = (float*)d_out;

    // ---------------- workspace layout ----------------
    // int region (element offsets):
    int* ib = (int*)d_ws;
    int* cnt_out0 = ib;                      // N0           (200000)
    int* cnt_in0  = cnt_out0 + N0;           // N1
    int* cnt_out1 = cnt_in0 + N1;            // N1
    int* cnt_in1  = cnt_out1 + N1;           // N2   -- counts total 310000, contiguous
    int* rank0    = cnt_in1 + N2;            // E0
    int* rank1    = rank0 + E0;              // E1
    int* rowptr0  = rank1 + E1;              // N1+1
    int* rowptr1  = rowptr0 + (N1 + 1);      // N2+1
    int* csr0     = rowptr1 + (N2 + 1);      // E0
    int* csr1     = csr0 + E0;               // E1
    int* iend     = csr1 + E1;               // 2,290,002 ints
    // float region, 16B-aligned (2290002 -> 2290004)
    float* fb = (float*)(ib + 2290004);
    float* rs_out0 = fb;                     // N0  (same order as counts)
    float* rs_in0  = rs_out0 + N0;           // N1
    float* rs_out1 = rs_in0 + N1;            // N1
    float* rs_in1  = rs_out1 + N1;           // N2  -- scales total 310000
    float* h1      = rs_in1 + N2 + 0;        // N1*256 = 12,800,000
    float* regA    = h1 + (size_t)N1 * 256;  // 12,800,000 floats, multi-use:
    float* agg0    = regA;                   //   N1*256 (full region)
    float* agg1    = regA;                   //   N2*256 (reuses agg0 space; agg0 dead after gemm1)
    float* h2      = regA + 3200000;         //   N2*256 (disjoint from agg1's 2,560,000)
    (void)iend;

    const int n_cnt = N0 + N1 + N1 + N2;     // 310000

    // 1. zero the count region only (ranks/rowptr/csr/agg are fully written before read)
    hipMemsetAsync(cnt_out0, 0, (size_t)n_cnt * sizeof(int), stream);

    // 2. degree counts + per-edge ranks
    count_kernel<<<(E0 + 255) / 256, 256, 0, stream>>>(src0, dst0, cnt_out0, cnt_in0, rank0, E0);
    count_kernel<<<(E1 + 255) / 256, 256, 0, stream>>>(src1, dst1, cnt_out1, cnt_in1, rank1, E1);

    // 3. scales = rsqrt(max(cnt,1)) for all 4 arrays at once
    scales_kernel<<<(n_cnt + 255) / 256, 256, 0, stream>>>(cnt_out0, rs_out0, n_cnt);

    // 4. rowptrs (exclusive scans of in-degree counts)
    scan_kernel<<<1, 1024, 0, stream>>>(cnt_in0, rowptr0, N1);
    scan_kernel<<<1, 1024, 0, stream>>>(cnt_in1, rowptr1, N2);

    // 5. CSR fill
    fill_kernel<<<(E0 + 255) / 256, 256, 0, stream>>>(src0, dst0, rank0, rowptr0, csr0, E0);
    fill_kernel<<<(E1 + 255) / 256, 256, 0, stream>>>(src1, dst1, rank1, rowptr1, csr1, E1);

    // 6. layer-1 gather: agg0[d] = sum_{e: dst=d} rs_out0[src] * h[src]
    gather_kernel<<<(N1 + 3) / 4, 256, 0, stream>>>(h, rs_out0, rowptr0, csr0, agg0, N1);

    // 7. h1 = (diag(rs_in0) agg0) @ W1 + b1    [50000 x 256]
    gemm_k256<<<dim3((N1 + 63) / 64, 4), 256, 0, stream>>>(agg0, rs_in0, W1, b1, h1, N1, 256);

    // 8. layer-2 gather: agg1[d] = sum rs_out1[src] * h1[src]
    gather_kernel<<<(N2 + 3) / 4, 256, 0, stream>>>(h1, rs_out1, rowptr1, csr1, agg1, N2);

    // 9. h2 = (diag(rs_in1) agg1) @ W2 + b2    [10000 x 256]
    gemm_k256<<<dim3((N2 + 63) / 64, 4), 256, 0, stream>>>(agg1, rs_in1, W2, b2, h2, N2, 256);

    // 10. out = h2 @ Wp + bp                   [10000 x 128]
    gemm_k256<<<dim3((N2 + 63) / 64, 2), 256, 0, stream>>>(h2, nullptr, Wp, bp, out, N2, 128);
}

// Round 3
// 711.606 us; speedup vs baseline: 5.1294x; 1.0525x over previous
//
#include <hip/hip_runtime.h>
#include <cstddef>

// Problem constants (from reference)
#define N0 200000
#define N1 50000
#define N2 10000
#define E0 800000
#define E1 160000
// feature dims: IN=H1=H2=256, EMB=128. K is always 256.

typedef short bf16x8 __attribute__((ext_vector_type(8)));   // 8 bf16 = 4 VGPRs
typedef float f32x4 __attribute__((ext_vector_type(4)));

__device__ __forceinline__ unsigned short f2bf(float f) {
    unsigned int u = __float_as_uint(f);
    unsigned int r = (u + 0x7FFF + ((u >> 16) & 1)) >> 16;   // RNE
    return (unsigned short)r;
}

// ---------------- pass A: out-degree count + in-degree count with per-edge rank ----------------
__global__ void count_kernel(const int* __restrict__ src, const int* __restrict__ dst,
                             int* __restrict__ out_cnt, int* __restrict__ in_cnt,
                             int* __restrict__ rank, int E) {
    int e = blockIdx.x * 256 + threadIdx.x;
    if (e < E) {
        atomicAdd(&out_cnt[src[e]], 1);
        rank[e] = atomicAdd(&in_cnt[dst[e]], 1);
    }
}

// ---------------- counts -> rsqrt(max(cnt,1)) scales ----------------
__global__ void scales_kernel(const int* __restrict__ cnt, float* __restrict__ rs, int n) {
    int i = blockIdx.x * 256 + threadIdx.x;
    if (i < n) rs[i] = rsqrtf((float)max(cnt[i], 1));
}

// ---------------- single-workgroup 3-phase exclusive scan: rowptr[0..n] ----------------
__global__ __launch_bounds__(1024) void scan_kernel(const int* __restrict__ cnt,
                                                    int* __restrict__ rowptr, int n) {
    __shared__ int partial[1024];
    const int t = threadIdx.x;
    const int chunk = (n + 1023) / 1024;
    const int begin = t * chunk;
    const int end = min(begin + chunk, n);
    int sum = 0;
    for (int i = begin; i < end; i++) sum += cnt[i];
    partial[t] = sum;
    __syncthreads();
    for (int off = 1; off < 1024; off <<= 1) {
        int v = (t >= off) ? partial[t - off] : 0;
        __syncthreads();
        partial[t] += v;
        __syncthreads();
    }
    int run = partial[t] - sum;
    for (int i = begin; i < end; i++) {
        rowptr[i] = run;
        run += cnt[i];
    }
    if (t == 1023) rowptr[n] = partial[1023];
}

// ---------------- pass C: drop src indices into CSR slots ----------------
__global__ void fill_kernel(const int* __restrict__ src, const int* __restrict__ dst,
                            const int* __restrict__ rank, const int* __restrict__ rowptr,
                            int* __restrict__ csr, int E) {
    int e = blockIdx.x * 256 + threadIdx.x;
    if (e < E) csr[rowptr[dst[e]] + rank[e]] = src[e];
}

// ---------------- gather: one wave per dst row, unroll-4, fused dst scale ----------------
__global__ __launch_bounds__(256) void gather_kernel(const float* __restrict__ hsrc,
                                                     const float* __restrict__ rs_src,
                                                     const float* __restrict__ rs_dst,
                                                     const int* __restrict__ rowptr,
                                                     const int* __restrict__ csr,
                                                     float* __restrict__ agg, int n_dst) {
    int w    = (blockIdx.x * 256 + threadIdx.x) >> 6;   // wave id = dst row
    int lane = threadIdx.x & 63;
    if (w >= n_dst) return;
    int e   = rowptr[w];
    int end = rowptr[w + 1];
    float4 acc = make_float4(0.f, 0.f, 0.f, 0.f);
    // unroll-4: four independent load chains in flight
    for (; e + 3 < end; e += 4) {
        int s0 = csr[e], s1 = csr[e + 1], s2 = csr[e + 2], s3 = csr[e + 3];
        float sc0 = rs_src[s0], sc1 = rs_src[s1], sc2 = rs_src[s2], sc3 = rs_src[s3];
        float4 v0 = ((const float4*)(hsrc + (size_t)s0 * 256))[lane];
        float4 v1 = ((const float4*)(hsrc + (size_t)s1 * 256))[lane];
        float4 v2 = ((const float4*)(hsrc + (size_t)s2 * 256))[lane];
        float4 v3 = ((const float4*)(hsrc + (size_t)s3 * 256))[lane];
        acc.x += v0.x * sc0; acc.y += v0.y * sc0; acc.z += v0.z * sc0; acc.w += v0.w * sc0;
        acc.x += v1.x * sc1; acc.y += v1.y * sc1; acc.z += v1.z * sc1; acc.w += v1.w * sc1;
        acc.x += v2.x * sc2; acc.y += v2.y * sc2; acc.z += v2.z * sc2; acc.w += v2.w * sc2;
        acc.x += v3.x * sc3; acc.y += v3.y * sc3; acc.z += v3.z * sc3; acc.w += v3.w * sc3;
    }
    for (; e < end; e++) {
        int s0 = csr[e];
        float sc0 = rs_src[s0];
        float4 v0 = ((const float4*)(hsrc + (size_t)s0 * 256))[lane];
        acc.x += v0.x * sc0; acc.y += v0.y * sc0; acc.z += v0.z * sc0; acc.w += v0.w * sc0;
    }
    float sd = rs_dst[w];
    acc.x *= sd; acc.y *= sd; acc.z *= sd; acc.w *= sd;
    ((float4*)(agg + (size_t)w * 256))[lane] = acc;
}

// ---------------- weight pre-pack: W [K][N] fp32 row-major -> B-fragment layout ----------------
// layout: Bp[ct][s][lane][j], ct = col-tile (16 cols), s = k-step (32 k), j = 0..7
// lane holds B[k = s*32 + (lane>>4)*8 + j][n = ct*16 + (lane&15)]
__global__ void pack_b_kernel(const float* __restrict__ W, unsigned short* __restrict__ Bp,
                              int K, int N) {
    int tid = blockIdx.x * 256 + threadIdx.x;
    int total = (N / 16) * (K / 32) * 64;
    if (tid >= total) return;
    int lane = tid & 63;
    int rest = tid >> 6;
    int s  = rest % (K / 32);
    int ct = rest / (K / 32);
    int col = ct * 16 + (lane & 15);
    int k0  = s * 32 + (lane >> 4) * 8;
    unsigned short* dst = Bp + (size_t)tid * 8;
#pragma unroll
    for (int j = 0; j < 8; j++) dst[j] = f2bf(W[(size_t)(k0 + j) * N + col]);
}

// ---------------- bf16 MFMA GEMM: C[M,N] = A[M,256] @ W + bias, A fp32, W pre-packed bf16 ----
// block = 256 threads = 4 waves; BM = 64 rows/block; wave w owns cols [w*NCT*16, (w+1)*NCT*16)
// NCT = col-tiles per wave: 4 for N=256, 2 for N=128. No LDS.
template <int NCT>
__global__ __launch_bounds__(256) void gemm_mfma(const float* __restrict__ A,
                                                 const unsigned short* __restrict__ Bp,
                                                 const float* __restrict__ bias,
                                                 float* __restrict__ C, int M, int N) {
    const int lane = threadIdx.x & 63;
    const int wave = threadIdx.x >> 6;            // 0..3
    const int rowBase = blockIdx.x * 64;
    const int colBase = wave * (NCT * 16);
    const int lm = lane & 15;                     // row-in-tile (A) / col-in-tile (B,C)
    const int quad = lane >> 4;                   // 0..3

    f32x4 acc[4][NCT];
#pragma unroll
    for (int rt = 0; rt < 4; rt++)
#pragma unroll
        for (int ct = 0; ct < NCT; ct++) acc[rt][ct] = (f32x4){0.f, 0.f, 0.f, 0.f};

    const float* ap[4];
#pragma unroll
    for (int rt = 0; rt < 4; rt++) {
        int r = min(rowBase + rt * 16 + lm, M - 1);
        ap[rt] = A + (size_t)r * 256 + quad * 8;
    }

#pragma unroll
    for (int s = 0; s < 8; s++) {                 // K = 256, 32 per step
        bf16x8 afrag[4];
#pragma unroll
        for (int rt = 0; rt < 4; rt++) {
            const float* p = ap[rt] + s * 32;
            float4 x = *(const float4*)p;
            float4 y = *(const float4*)(p + 4);
            union { unsigned short u[8]; bf16x8 v; } af;
            af.u[0] = f2bf(x.x); af.u[1] = f2bf(x.y); af.u[2] = f2bf(x.z); af.u[3] = f2bf(x.w);
            af.u[4] = f2bf(y.x); af.u[5] = f2bf(y.y); af.u[6] = f2bf(y.z); af.u[7] = f2bf(y.w);
            afrag[rt] = af.v;
        }
#pragma unroll
        for (int ct = 0; ct < NCT; ct++) {
            bf16x8 bfrag = *(const bf16x8*)(Bp + (((size_t)(wave * NCT + ct) * 8 + s) * 64 + lane) * 8);
#pragma unroll
            for (int rt = 0; rt < 4; rt++)
                acc[rt][ct] = __builtin_amdgcn_mfma_f32_16x16x32_bf16(afrag[rt], bfrag, acc[rt][ct], 0, 0, 0);
        }
    }

    // epilogue: C layout col=lane&15, row=quad*4+i
#pragma unroll
    for (int ct = 0; ct < NCT; ct++) {
        float bv = bias[colBase + ct * 16 + lm];
#pragma unroll
        for (int rt = 0; rt < 4; rt++) {
#pragma unroll
            for (int i = 0; i < 4; i++) {
                int row = rowBase + rt * 16 + quad * 4 + i;
                if (row < M) C[(size_t)row * N + colBase + ct * 16 + lm] = acc[rt][ct][i] + bv;
            }
        }
    }
}

extern "C" void kernel_launch(void* const* d_in, const int* in_sizes, int n_in,
                              void* d_out, int out_size, void* d_ws, size_t ws_size,
                              hipStream_t stream) {
    const float* h    = (const float*)d_in[0];
    const int*   src0 = (const int*)d_in[1];
    const int*   dst0 = (const int*)d_in[2];
    const int*   src1 = (const int*)d_in[3];
    const int*   dst1 = (const int*)d_in[4];
    const float* W1   = (const float*)d_in[5];
    const float* b1   = (const float*)d_in[6];
    const float* W2   = (const float*)d_in[7];
    const float* b2   = (const float*)d_in[8];
    const float* Wp   = (const float*)d_in[9];
    const float* bp   = (const float*)d_in[10];
    float* out = (float*)d_out;

    // ---------------- workspace layout ----------------
    int* ib = (int*)d_ws;
    int* cnt_out0 = ib;                      // N0
    int* cnt_in0  = cnt_out0 + N0;           // N1
    int* cnt_out1 = cnt_in0 + N1;            // N1
    int* cnt_in1  = cnt_out1 + N1;           // N2   counts total 310000, contiguous
    int* rank0    = cnt_in1 + N2;            // E0
    int* rank1    = rank0 + E0;              // E1
    int* rowptr0  = rank1 + E1;              // N1+1
    int* rowptr1  = rowptr0 + (N1 + 1);      // N2+1
    int* csr0     = rowptr1 + (N2 + 1);      // E0
    int* csr1     = csr0 + E0;               // E1   -> 2,290,002 ints
    // float region, 16B-aligned
    float* fb = (float*)(ib + 2290004);
    float* rs_out0 = fb;                     // N0
    float* rs_in0  = rs_out0 + N0;           // N1
    float* rs_out1 = rs_in0 + N1;            // N1
    float* rs_in1  = rs_out1 + N1;           // N2   scales total 310000
    float* h1      = rs_in1 + N2;            // N1*256 = 12,800,000
    float* regA    = h1 + (size_t)N1 * 256;  // 12,800,000 floats, multi-use:
    float* agg0    = regA;                   //   N1*256
    float* agg1    = regA;                   //   N2*256 (agg0 dead after gemm1)
    float* h2      = regA + 3200000;         //   N2*256 (disjoint from agg1)
    // packed weights (bf16) after regA
    unsigned short* W1p = (unsigned short*)(regA + (size_t)N1 * 256);  // 256*256
    unsigned short* W2p = W1p + 256 * 256;                             // 256*256
    unsigned short* Wpp = W2p + 256 * 256;                             // 256*128

    const int n_cnt = N0 + N1 + N1 + N2;     // 310000

    // 1. zero the count region
    hipMemsetAsync(cnt_out0, 0, (size_t)n_cnt * sizeof(int), stream);

    // 2. weight pre-pack (tiny; W tiles L2-resident)
    pack_b_kernel<<<(16 * 8 * 64 + 255) / 256, 256, 0, stream>>>(W1, W1p, 256, 256);
    pack_b_kernel<<<(16 * 8 * 64 + 255) / 256, 256, 0, stream>>>(W2, W2p, 256, 256);
    pack_b_kernel<<<(8 * 8 * 64 + 255) / 256, 256, 0, stream>>>(Wp, Wpp, 256, 128);

    // 3. degree counts + per-edge ranks
    count_kernel<<<(E0 + 255) / 256, 256, 0, stream>>>(src0, dst0, cnt_out0, cnt_in0, rank0, E0);
    count_kernel<<<(E1 + 255) / 256, 256, 0, stream>>>(src1, dst1, cnt_out1, cnt_in1, rank1, E1);

    // 4. scales = rsqrt(max(cnt,1))
    scales_kernel<<<(n_cnt + 255) / 256, 256, 0, stream>>>(cnt_out0, rs_out0, n_cnt);

    // 5. rowptrs
    scan_kernel<<<1, 1024, 0, stream>>>(cnt_in0, rowptr0, N1);
    scan_kernel<<<1, 1024, 0, stream>>>(cnt_in1, rowptr1, N2);

    // 6. CSR fill
    fill_kernel<<<(E0 + 255) / 256, 256, 0, stream>>>(src0, dst0, rank0, rowptr0, csr0, E0);
    fill_kernel<<<(E1 + 255) / 256, 256, 0, stream>>>(src1, dst1, rank1, rowptr1, csr1, E1);

    // 7. layer-1 gather (src scale + dst scale fused)
    gather_kernel<<<(N1 + 3) / 4, 256, 0, stream>>>(h, rs_out0, rs_in0, rowptr0, csr0, agg0, N1);

    // 8. h1 = agg0 @ W1 + b1    [50000 x 256]
    gemm_mfma<4><<<(N1 + 63) / 64, 256, 0, stream>>>(agg0, W1p, b1, h1, N1, 256);

    // 9. layer-2 gather
    gather_kernel<<<(N2 + 3) / 4, 256, 0, stream>>>(h1, rs_out1, rs_in1, rowptr1, csr1, agg1, N2);

    // 10. h2 = agg1 @ W2 + b2   [10000 x 256]
    gemm_mfma<4><<<(N2 + 63) / 64, 256, 0, stream>>>(agg1, W2p, b2, h2, N2, 256);

    // 11. out = h2 @ Wp + bp    [10000 x 128]
    gemm_mfma<2><<<(N2 + 63) / 64, 256, 0, stream>>>(h2, Wpp, bp, out, N2, 128);
}